// Round 3
// baseline (10715.717 us; speedup 1.0000x reference)
//
#include <hip/hip_runtime.h>

#define T_LEN 1024
#define DIN   512
#define HID   1024
#define NWG   64   // 32 WGs layer0 + 32 WGs layer1

typedef __attribute__((ext_vector_type(8))) short short8;  // 8 x bf16 bits (MFMA frag)
typedef __attribute__((ext_vector_type(4))) float f4;
typedef unsigned long long u64;

__device__ __forceinline__ unsigned short f2bf(float f) {
  union { float f; unsigned u; } v; v.f = f;
  return (unsigned short)((v.u + 0x7FFFu + ((v.u >> 16) & 1u)) >> 16);  // RNE
}
__device__ __forceinline__ float bf2f(unsigned short b) {
  union { unsigned u; float f; } v; v.u = ((unsigned)b) << 16; return v.f;
}
__device__ __forceinline__ short8 cvt8(f4 a, f4 b) {
  short8 r;
  r[0]=(short)f2bf(a[0]); r[1]=(short)f2bf(a[1]); r[2]=(short)f2bf(a[2]); r[3]=(short)f2bf(a[3]);
  r[4]=(short)f2bf(b[0]); r[5]=(short)f2bf(b[1]); r[6]=(short)f2bf(b[2]); r[7]=(short)f2bf(b[3]);
  return r;
}
__device__ __forceinline__ void cvt8hl(f4 a, f4 b, short8& hi, short8& lo) {
  hi = cvt8(a, b);
  f4 ra, rb;
#pragma unroll
  for (int j = 0; j < 4; ++j) {
    ra[j] = a[j] - bf2f((unsigned short)hi[j]);
    rb[j] = b[j] - bf2f((unsigned short)hi[4 + j]);
  }
  lo = cvt8(ra, rb);
}
__device__ __forceinline__ float tanh_fast(float x) {
  float e = __expf(2.f * x);
  return 1.f - 2.f / (e + 1.f);
}
__device__ __forceinline__ f4 mfma16(short8 a, short8 b, f4 c) {
  return __builtin_amdgcn_mfma_f32_16x16x32_bf16(a, b, c, 0, 0, 0);
}
// 3-term compensated bf16 product: (ah+al)*(bh+bl) ~= ah*bh + al*bh + ah*bl
__device__ __forceinline__ f4 fma3(short8 ah, short8 al, short8 bh, short8 bl, f4 c) {
  c = mfma16(ah, bh, c);
  c = mfma16(al, bh, c);
  c = mfma16(ah, bl, c);
  return c;
}

// Coherent fragment-pair load from a ring parity (hi plane + lo plane).
// Plane layout (ushort units): off16(b,k) = ((k>>5)*2+(b>>4))*512 + (((k>>3)&3)*16+(b&15))*8 + (k&7)
// => per (K32,half) block of 1KB, lane's 16B at lane*16. lo plane at +65536 B.
__device__ __forceinline__ void ld_fragpair(const char* par, int K32, int hf, int lane,
                                            short8& hi, short8& lo) {
  const u64* q = (const u64*)par + (size_t)(K32 * 2 + hf) * 128 + lane * 2;
  union U { u64 q[2]; short8 s; } a, b;
  a.q[0] = __hip_atomic_load((u64*)(q + 0),    __ATOMIC_RELAXED, __HIP_MEMORY_SCOPE_AGENT);
  a.q[1] = __hip_atomic_load((u64*)(q + 1),    __ATOMIC_RELAXED, __HIP_MEMORY_SCOPE_AGENT);
  b.q[0] = __hip_atomic_load((u64*)(q + 8192), __ATOMIC_RELAXED, __HIP_MEMORY_SCOPE_AGENT);
  b.q[1] = __hip_atomic_load((u64*)(q + 8193), __ATOMIC_RELAXED, __HIP_MEMORY_SCOPE_AGENT);
  hi = a.s; lo = b.s;
}

// Zero rings + flags: 1052672 bytes = 263168 dwords at ws base.
__global__ void prep_kernel(unsigned int* __restrict__ z) {
  z[blockIdx.x * 256 + threadIdx.x] = 0u;
}

// Persistent fused 2-layer RNN, split-layer flag sync, 4-deep h rings.
// WG wg: layer=wg>>5, output cols [(wg&31)*32,+32). 4 waves split K.
// hi-weights in regs; lo-weights in private L2-cached global scratch.
__global__ __launch_bounds__(256, 1)
void rnn_fused(const float* __restrict__ x,
               const float* __restrict__ Wih0, const float* __restrict__ Whh0,
               const float* __restrict__ bi0,  const float* __restrict__ bh0,
               const float* __restrict__ Wih1, const float* __restrict__ Whh1,
               const float* __restrict__ bi1,  const float* __restrict__ bh1,
               char* __restrict__ h0ring, char* __restrict__ h1ring,
               int* __restrict__ flags, short8* __restrict__ wloG,
               float* __restrict__ outy, float* __restrict__ outh) {
  const int wg    = blockIdx.x;
  const int layer = wg >> 5;
  const int i_base = (wg & 31) * 32;
  const int tid  = threadIdx.x;
  const int wv   = tid >> 6;
  const int lane = tid & 63;
  const int l15  = lane & 15;
  const int kb   = lane >> 4;

  const float* Wih = layer ? Wih1 : Wih0;
  const float* Whh = layer ? Whh1 : Whh0;
  const int K1   = layer ? HID : DIN;
  const int npre = layer ? 8 : 4;
  char* ringW = layer ? h1ring : h0ring;

  __shared__ float red[4][4][64][4];   // [wave][frag][lane][reg] 16 KB

  // ---- hoist hi-weights to regs; lo-weights to private global scratch ----
  short8 bpre[8][2], brhi[8][2];
  short8* wlb = wloG + (size_t)(wg * 4 + wv) * 2048;   // 32 KB per (wg,wv)
#pragma unroll
  for (int kk = 0; kk < 8; ++kk) {
#pragma unroll
    for (int nfj = 0; nfj < 2; ++nfj) {
      if (kk < npre) {
        int k = wv * (K1 >> 2) + kk * 32 + kb * 8;
        const float* sp = Wih + (size_t)(i_base + nfj * 16 + l15) * K1 + k;
        short8 hi, lo;
        cvt8hl(*(const f4*)sp, *(const f4*)(sp + 4), hi, lo);
        bpre[kk][nfj] = hi;
        wlb[(kk * 2 + nfj) * 64 + lane] = lo;
      }
      {
        int k = wv * 256 + kk * 32 + kb * 8;
        const float* sp = Whh + (size_t)(i_base + nfj * 16 + l15) * HID + k;
        short8 hi, lo;
        cvt8hl(*(const f4*)sp, *(const f4*)(sp + 4), hi, lo);
        brhi[kk][nfj] = hi;
        wlb[(16 + kk * 2 + nfj) * 64 + lane] = lo;
      }
    }
  }

  const int emh = wv & 1, enf = wv >> 1;      // this wave finalizes frag wv
  const int e_i = i_base + enf * 16 + l15;    // global output col
  const float biasv = layer ? (bi1[e_i] + bh1[e_i]) : (bi0[e_i] + bh0[e_i]);
  const int K32w = wg & 31;
  const int lane_c = (enf * 2 + (l15 >> 3)) * 16 + kb * 4;          // + rr
  const int dwbase = (K32w * 2 + emh) * 256 + lane_c * 4 + ((e_i & 7) >> 1);

  // ---- split-layer wait setup: flag[w] = steps completed by WG w ----
  int fidx, foff;
  if (layer == 0) { fidx = lane;                              foff = (lane < 32) ? 0 : -2; }
  else            { fidx = (lane < 32) ? (32 + lane) : (lane - 32); foff = (lane < 32) ? 0 : 1; }
  int* flagp = flags + fidx * 4;

  for (int t = 0; t < T_LEN; ++t) {
    // ---- wait: L0 needs {L0>=t, L1>=t-2}; L1 needs {L1>=t, L0>=t+1} ----
    {
      const int thr = t + foff;
      while (__hip_atomic_load(flagp, __ATOMIC_RELAXED, __HIP_MEMORY_SCOPE_AGENT) < thr)
        __builtin_amdgcn_s_sleep(1);
    }

    f4 acc0 = {0.f,0.f,0.f,0.f}, acc1 = acc0, acc2 = acc0, acc3 = acc0;

    // ---- input projection ----
    if (layer == 0) {
      const float* xr0 = x + ((size_t)l15 * T_LEN + t) * DIN;
      const float* xr1 = x + ((size_t)(16 + l15) * T_LEN + t) * DIN;
#pragma unroll
      for (int kk = 0; kk < 4; ++kk) {
        int k = wv * 128 + kk * 32 + kb * 8;
        short8 a0h, a0l, a1h, a1l;
        cvt8hl(*(const f4*)(xr0 + k), *(const f4*)(xr0 + k + 4), a0h, a0l);
        cvt8hl(*(const f4*)(xr1 + k), *(const f4*)(xr1 + k + 4), a1h, a1l);
        short8 bl0 = wlb[(kk * 2 + 0) * 64 + lane];
        short8 bl1 = wlb[(kk * 2 + 1) * 64 + lane];
        acc0 = fma3(a0h, a0l, bpre[kk][0], bl0, acc0);
        acc1 = fma3(a1h, a1l, bpre[kk][0], bl0, acc1);
        acc2 = fma3(a0h, a0l, bpre[kk][1], bl1, acc2);
        acc3 = fma3(a1h, a1l, bpre[kk][1], bl1, acc3);
      }
    } else {
      const char* y0 = h0ring + (size_t)((t + 1) & 3) * 131072;   // layer0 output at step t
#pragma unroll
      for (int kk = 0; kk < 8; ++kk) {
        short8 a0h, a0l, a1h, a1l;
        ld_fragpair(y0, wv * 8 + kk, 0, lane, a0h, a0l);
        ld_fragpair(y0, wv * 8 + kk, 1, lane, a1h, a1l);
        short8 bl0 = wlb[(kk * 2 + 0) * 64 + lane];
        short8 bl1 = wlb[(kk * 2 + 1) * 64 + lane];
        acc0 = fma3(a0h, a0l, bpre[kk][0], bl0, acc0);
        acc1 = fma3(a1h, a1l, bpre[kk][0], bl0, acc1);
        acc2 = fma3(a0h, a0l, bpre[kk][1], bl1, acc2);
        acc3 = fma3(a1h, a1l, bpre[kk][1], bl1, acc3);
      }
    }

    // ---- recurrent part ----
    {
      const char* rec = ringW + (size_t)(t & 3) * 131072;
#pragma unroll
      for (int kk = 0; kk < 8; ++kk) {
        short8 a0h, a0l, a1h, a1l;
        ld_fragpair(rec, wv * 8 + kk, 0, lane, a0h, a0l);
        ld_fragpair(rec, wv * 8 + kk, 1, lane, a1h, a1l);
        short8 bl0 = wlb[(16 + kk * 2 + 0) * 64 + lane];
        short8 bl1 = wlb[(16 + kk * 2 + 1) * 64 + lane];
        acc0 = fma3(a0h, a0l, brhi[kk][0], bl0, acc0);
        acc1 = fma3(a1h, a1l, brhi[kk][0], bl0, acc1);
        acc2 = fma3(a0h, a0l, brhi[kk][1], bl1, acc2);
        acc3 = fma3(a1h, a1l, brhi[kk][1], bl1, acc3);
      }
    }

    // ---- cross-wave K reduction via LDS ----
    *(f4*)&red[wv][0][lane][0] = acc0;
    *(f4*)&red[wv][1][lane][0] = acc1;
    *(f4*)&red[wv][2][lane][0] = acc2;
    *(f4*)&red[wv][3][lane][0] = acc3;
    __syncthreads();
    f4 tot = *(const f4*)&red[0][wv][lane][0];
    tot += *(const f4*)&red[1][wv][lane][0];
    tot += *(const f4*)&red[2][wv][lane][0];
    tot += *(const f4*)&red[3][wv][lane][0];

    // ---- epilogue: bias+tanh; paired dword stores to hi/lo planes ----
    // C/D layout: col = lane&15, row = (lane>>4)*4 + reg  [m89]
    unsigned int* wrHi = (unsigned int*)(ringW + (size_t)((t + 1) & 3) * 131072);
    unsigned int* wrLo = wrHi + 16384;
#pragma unroll
    for (int rr = 0; rr < 4; ++rr) {
      const int b = emh * 16 + kb * 4 + rr;
      float v = tanh_fast(tot[rr] + biasv);
      unsigned short hi = f2bf(v);
      unsigned short lo = f2bf(v - bf2f(hi));
      unsigned int pk = (unsigned int)hi | ((unsigned int)lo << 16);
      unsigned int oth = __shfl_xor(pk, 1, 64);
      const int dw = dwbase + rr * 4;
      if ((l15 & 1) == 0)
        __hip_atomic_store(wrHi + dw, (pk & 0xffffu) | ((oth & 0xffffu) << 16),
                           __ATOMIC_RELAXED, __HIP_MEMORY_SCOPE_AGENT);
      else
        __hip_atomic_store(wrLo + dw, (oth >> 16) | ((pk >> 16) << 16),
                           __ATOMIC_RELAXED, __HIP_MEMORY_SCOPE_AGENT);
      if (layer == 0) {
        if (t == T_LEN - 1) outh[(size_t)b * HID + e_i] = v;
      } else {
        float vo = __shfl_xor(v, 1, 64);
        if ((l15 & 1) == 0)
          *(float2*)&outy[((size_t)b * T_LEN + t) * HID + e_i] = make_float2(v, vo);
        if (t == T_LEN - 1) outh[32768 + (size_t)b * HID + e_i] = v;
      }
    }

    __syncthreads();   // drains every wave's UC stores (vmcnt(0) before s_barrier)
    if (tid == 0)
      __hip_atomic_store(flags + wg * 4, t + 1, __ATOMIC_RELAXED, __HIP_MEMORY_SCOPE_AGENT);
  }
}

extern "C" void kernel_launch(void* const* d_in, const int* in_sizes, int n_in,
                              void* d_out, int out_size, void* d_ws, size_t ws_size,
                              hipStream_t stream) {
  const float* x    = (const float*)d_in[0];
  const float* Wih0 = (const float*)d_in[1];
  const float* Whh0 = (const float*)d_in[2];
  const float* bi0  = (const float*)d_in[3];
  const float* bh0  = (const float*)d_in[4];
  const float* Wih1 = (const float*)d_in[5];
  const float* Whh1 = (const float*)d_in[6];
  const float* bi1  = (const float*)d_in[7];
  const float* bh1  = (const float*)d_in[8];

  float* outy = (float*)d_out;
  float* outh = outy + (size_t)32 * 1024 * 1024;   // [2][32][1024] tail

  char* ws = (char*)d_ws;
  char*   h0ring = ws;                              // 4 parities x 131072 B (hi+lo planes)
  char*   h1ring = ws + 524288;
  int*    flg    = (int*)(ws + 1048576);            // 64 flags x 16 B
  short8* wloG   = (short8*)(ws + 1052672);         // 64 WG x 4 wv x 32 KB = 8 MB

  prep_kernel<<<1028, 256, 0, stream>>>((unsigned int*)ws);   // zero rings + flags
  rnn_fused<<<NWG, 256, 0, stream>>>(x, Wih0, Whh0, bi0, bh0,
                                     Wih1, Whh1, bi1, bh1,
                                     h0ring, h1ring, flg, wloG, outy, outh);
}

// Round 5
// 8399.496 us; speedup vs baseline: 1.2758x; 1.2758x over previous
//
#include <hip/hip_runtime.h>

#define T_LEN 1024
#define DIN   512
#define HID   1024
#define NWG   64   // 32 WGs layer0 + 32 WGs layer1
#define RING  8

typedef __attribute__((ext_vector_type(8))) short short8;  // 8 x bf16 bits (MFMA frag)
typedef __attribute__((ext_vector_type(4))) float f4;
typedef unsigned long long u64;
typedef unsigned short u16;

#define LD_AG(p)    __hip_atomic_load((p),  __ATOMIC_RELAXED, __HIP_MEMORY_SCOPE_AGENT)
#define ST_AG(p, v) __hip_atomic_store((p), (v), __ATOMIC_RELAXED, __HIP_MEMORY_SCOPE_AGENT)

__device__ __forceinline__ u16 f2bf(float f) {
  union { float f; unsigned u; } v; v.f = f;
  return (u16)((v.u + 0x7FFFu + ((v.u >> 16) & 1u)) >> 16);  // RNE
}
__device__ __forceinline__ float bf2f(u16 b) {
  union { unsigned u; float f; } v; v.u = ((unsigned)b) << 16; return v.f;
}
__device__ __forceinline__ short8 cvt8(f4 a, f4 b) {
  short8 r;
  r[0]=(short)f2bf(a[0]); r[1]=(short)f2bf(a[1]); r[2]=(short)f2bf(a[2]); r[3]=(short)f2bf(a[3]);
  r[4]=(short)f2bf(b[0]); r[5]=(short)f2bf(b[1]); r[6]=(short)f2bf(b[2]); r[7]=(short)f2bf(b[3]);
  return r;
}
__device__ __forceinline__ void cvt8hl(f4 a, f4 b, short8& hi, short8& lo) {
  hi = cvt8(a, b);
  f4 ra, rb;
#pragma unroll
  for (int j = 0; j < 4; ++j) {
    ra[j] = a[j] - bf2f((u16)hi[j]);
    rb[j] = b[j] - bf2f((u16)hi[4 + j]);
  }
  lo = cvt8(ra, rb);
}
__device__ __forceinline__ float tanh_fast(float x) {
  float e = __expf(2.f * x);
  return 1.f - 2.f / (e + 1.f);
}
__device__ __forceinline__ f4 mfma16(short8 a, short8 b, f4 c) {
  return __builtin_amdgcn_mfma_f32_16x16x32_bf16(a, b, c, 0, 0, 0);
}
// 3-term compensated bf16 product: (ah+al)*(bh+bl) ~= ah*bh + al*bh + ah*bl
__device__ __forceinline__ f4 fma3(short8 ah, short8 al, short8 bh, short8 bl, f4 c) {
  c = mfma16(ah, bh, c);
  c = mfma16(al, bh, c);
  c = mfma16(ah, bl, c);
  return c;
}

// Coherent fragment-pair load. Ring parity layout (bytes):
//   hi plane: ((K32*2+hf)*64 + lane)*16 ; lo plane at +65536.
// Consumer lane ln of block (K32,hf): b = hf*16+(ln&15), k = K32*32+(ln>>4)*8+j.
__device__ __forceinline__ void ld_frag(const char* par, int K32, int hf, int lane,
                                        short8& hi, short8& lo) {
  const u64* q = (const u64*)(par + (size_t)(((K32 * 2 + hf) * 64 + lane) * 16));
  union U { u64 q[2]; short8 s; } a, b;
  a.q[0] = LD_AG((u64*)(q + 0));
  a.q[1] = LD_AG((u64*)(q + 1));
  b.q[0] = LD_AG((u64*)(q + 8192));   // +65536 B
  b.q[1] = LD_AG((u64*)(q + 8193));
  hi = a.s; lo = b.s;
}

// Zero parity-0 of both rings + flags.  ws dwords: h0 parity0 [0,32768),
// h1 parity0 at dword 262144, flags at dword 524288.
__global__ void prep_kernel(unsigned int* __restrict__ z) {
  int i = blockIdx.x * 256 + threadIdx.x;          // 128 blocks -> 32768 threads
  z[i] = 0u;                                       // h0 parity 0 (128 KB)
  z[262144 + i] = 0u;                              // h1 parity 0
  if (i < 256) z[524288 + i] = 0u;                 // flags (1 KB)
}

// Persistent fused 2-layer RNN; split-layer flag sync; 8-deep h rings.
// WG wg: layer=wg>>5, output cols [(wg&31)*32,+32). 4 waves split K.
// All weights (hi/lo bf16 pairs) in registers. Producer h-stores coalesced
// via LDS 32x32 transpose (each WG's tile == one consumer K32 block).
// Sync: EVERY wave spin-polls all 64 dep flags via its 64 lanes (wave-lockstep
// exit) — each wave's own atomic poll orders its subsequent ring loads;
// no reliance on barrier-release visibility (round-4 replay race).
__global__ __launch_bounds__(256, 1)
void rnn_fused(const float* __restrict__ x,
               const float* __restrict__ Wih0, const float* __restrict__ Whh0,
               const float* __restrict__ bi0,  const float* __restrict__ bh0,
               const float* __restrict__ Wih1, const float* __restrict__ Whh1,
               const float* __restrict__ bi1,  const float* __restrict__ bh1,
               char* __restrict__ h0ring, char* __restrict__ h1ring,
               int* __restrict__ flags,
               float* __restrict__ outy, float* __restrict__ outh) {
  const int wg    = blockIdx.x;
  const int layer = wg >> 5;
  const int i_base = (wg & 31) * 32;
  const int tid  = threadIdx.x;
  const int wv   = tid >> 6;
  const int lane = tid & 63;
  const int l15  = lane & 15;
  const int kb   = lane >> 4;

  const float* Wih = layer ? Wih1 : Wih0;
  const float* Whh = layer ? Whh1 : Whh0;
  const int K1   = layer ? HID : DIN;
  const int npre = layer ? 8 : 4;
  char* ringW = layer ? h1ring : h0ring;

  __shared__ float red[4][4][64][4];     // [wave][frag][lane][reg] 16 KB
  __shared__ u16 trh[32][36];            // 32x32 tile +pad (rows 72 B, u64-aligned)
  __shared__ u16 trl[32][36];

  // ---- hoist ALL weights to registers as bf16 hi/lo pairs (read once) ----
  short8 bpre[8][2], bprl[8][2], brhi[8][2], brlo[8][2];
#pragma unroll
  for (int kk = 0; kk < 8; ++kk) {
#pragma unroll
    for (int nfj = 0; nfj < 2; ++nfj) {
      if (kk < npre) {
        int k = wv * (K1 >> 2) + kk * 32 + kb * 8;
        const float* sp = Wih + (size_t)(i_base + nfj * 16 + l15) * K1 + k;
        cvt8hl(*(const f4*)sp, *(const f4*)(sp + 4), bpre[kk][nfj], bprl[kk][nfj]);
      }
      {
        int k = wv * 256 + kk * 32 + kb * 8;
        const float* sp = Whh + (size_t)(i_base + nfj * 16 + l15) * HID + k;
        cvt8hl(*(const f4*)sp, *(const f4*)(sp + 4), brhi[kk][nfj], brlo[kk][nfj]);
      }
    }
  }

  const int emh = wv & 1, enf = wv >> 1;      // this wave finalizes frag wv
  const int e_i = i_base + enf * 16 + l15;    // global output col
  const float biasv = layer ? (bi1[e_i] + bh1[e_i]) : (bi0[e_i] + bh0[e_i]);
  const int K32w = wg & 31;

  // ---- split-layer wait mapping (per-lane dep; wave-lockstep spin) ----
  // L0: lanes<32 -> L0 peers thr=t; lanes>=32 -> L1 WGs thr=t-4 (ring-8 anti-dep)
  // L1: lanes<32 -> L1 peers thr=t; lanes>=32 -> L0 WGs thr=t+1 (y0[t] ready)
  int fidx, foff;
  if (layer == 0) { fidx = lane;                               foff = (lane < 32) ? 0 : -4; }
  else            { fidx = (lane < 32) ? (32 + lane) : (lane - 32); foff = (lane < 32) ? 0 : 1; }
  int* flagp = flags + fidx * 4;

  for (int t = 0; t < T_LEN; ++t) {
    // ---- wait: every wave checks ALL deps (lanes exit in lockstep) ----
    {
      const int thr = t + foff;
      while (LD_AG(flagp) < thr)
        __builtin_amdgcn_s_sleep(2);
    }
    __builtin_amdgcn_sched_barrier(0);

    f4 acc0 = {0.f,0.f,0.f,0.f}, acc1 = acc0, acc2 = acc0, acc3 = acc0;

    // ---- input projection ----
    if (layer == 0) {
      const float* xr0 = x + ((size_t)l15 * T_LEN + t) * DIN;
      const float* xr1 = x + ((size_t)(16 + l15) * T_LEN + t) * DIN;
#pragma unroll
      for (int kk = 0; kk < 4; ++kk) {
        int k = wv * 128 + kk * 32 + kb * 8;
        short8 a0h, a0l, a1h, a1l;
        cvt8hl(*(const f4*)(xr0 + k), *(const f4*)(xr0 + k + 4), a0h, a0l);
        cvt8hl(*(const f4*)(xr1 + k), *(const f4*)(xr1 + k + 4), a1h, a1l);
        acc0 = fma3(a0h, a0l, bpre[kk][0], bprl[kk][0], acc0);
        acc1 = fma3(a1h, a1l, bpre[kk][0], bprl[kk][0], acc1);
        acc2 = fma3(a0h, a0l, bpre[kk][1], bprl[kk][1], acc2);
        acc3 = fma3(a1h, a1l, bpre[kk][1], bprl[kk][1], acc3);
      }
    } else {
      const char* y0 = h0ring + (size_t)((t + 1) & (RING - 1)) * 131072;
#pragma unroll
      for (int kk = 0; kk < 8; ++kk) {
        short8 a0h, a0l, a1h, a1l;
        ld_frag(y0, wv * 8 + kk, 0, lane, a0h, a0l);
        ld_frag(y0, wv * 8 + kk, 1, lane, a1h, a1l);
        acc0 = fma3(a0h, a0l, bpre[kk][0], bprl[kk][0], acc0);
        acc1 = fma3(a1h, a1l, bpre[kk][0], bprl[kk][0], acc1);
        acc2 = fma3(a0h, a0l, bpre[kk][1], bprl[kk][1], acc2);
        acc3 = fma3(a1h, a1l, bpre[kk][1], bprl[kk][1], acc3);
      }
    }

    // ---- recurrent part ----
    {
      const char* rec = ringW + (size_t)(t & (RING - 1)) * 131072;
#pragma unroll
      for (int kk = 0; kk < 8; ++kk) {
        short8 a0h, a0l, a1h, a1l;
        ld_frag(rec, wv * 8 + kk, 0, lane, a0h, a0l);
        ld_frag(rec, wv * 8 + kk, 1, lane, a1h, a1l);
        acc0 = fma3(a0h, a0l, brhi[kk][0], brlo[kk][0], acc0);
        acc1 = fma3(a1h, a1l, brhi[kk][0], brlo[kk][0], acc1);
        acc2 = fma3(a0h, a0l, brhi[kk][1], brlo[kk][1], acc2);
        acc3 = fma3(a1h, a1l, brhi[kk][1], brlo[kk][1], acc3);
      }
    }

    // ---- cross-wave K reduction via LDS ----
    *(f4*)&red[wv][0][lane][0] = acc0;
    *(f4*)&red[wv][1][lane][0] = acc1;
    *(f4*)&red[wv][2][lane][0] = acc2;
    *(f4*)&red[wv][3][lane][0] = acc3;
    __syncthreads();
    f4 tot = *(const f4*)&red[0][wv][lane][0];
    tot += *(const f4*)&red[1][wv][lane][0];
    tot += *(const f4*)&red[2][wv][lane][0];
    tot += *(const f4*)&red[3][wv][lane][0];

    // ---- value loop: bias+tanh, split hi/lo into LDS transpose tile ----
    // C/D layout: col = lane&15, row = (lane>>4)*4 + reg  [m89]
    float vkeep[4];
    const int c_col = enf * 16 + l15;
#pragma unroll
    for (int rr = 0; rr < 4; ++rr) {
      const int b = emh * 16 + kb * 4 + rr;
      float v = tanh_fast(tot[rr] + biasv);
      vkeep[rr] = v;
      u16 hi = f2bf(v);
      u16 lo = f2bf(v - bf2f(hi));
      trh[b][c_col] = hi;
      trl[b][c_col] = lo;
    }
    __syncthreads();   // tile ready

    // ---- coalesced coherent h-store: wave -> (plane=wv>>1, hf=wv&1) ----
    // lane ln: b = hf*16+(ln&15), cols (ln>>4)*8..+7  => one 16B chunk at lane*16
    {
      char* wr = ringW + (size_t)((t + 1) & (RING - 1)) * 131072 + (wv >> 1) * 65536;
      const int hf2 = wv & 1;
      const u16* srow = (wv >> 1) ? &trl[hf2 * 16 + l15][kb * 8] : &trh[hf2 * 16 + l15][kb * 8];
      const u64* sq = (const u64*)srow;
      u64* d = (u64*)(wr + (size_t)(((K32w * 2 + hf2) * 64 + lane) * 16));
      ST_AG(d + 0, sq[0]);
      ST_AG(d + 1, sq[1]);
    }
    // explicit drain: all h-stores globally visible before the flag publish
    asm volatile("s_waitcnt vmcnt(0)" ::: "memory");
    __syncthreads();
    if (tid == 0)
      ST_AG(flags + wg * 4, t + 1);

    // ---- deferred outputs (off the critical drain) ----
    if (layer == 0) {
      if (t == T_LEN - 1) {
#pragma unroll
        for (int rr = 0; rr < 4; ++rr)
          outh[(size_t)(emh * 16 + kb * 4 + rr) * HID + e_i] = vkeep[rr];
      }
    } else {
#pragma unroll
      for (int rr = 0; rr < 4; ++rr) {
        const int b = emh * 16 + kb * 4 + rr;
        float vo = __shfl_xor(vkeep[rr], 1, 64);
        if ((l15 & 1) == 0)
          *(float2*)&outy[((size_t)b * T_LEN + t) * HID + e_i] = make_float2(vkeep[rr], vo);
        if (t == T_LEN - 1) outh[32768 + (size_t)b * HID + e_i] = vkeep[rr];
      }
    }
  }
}

extern "C" void kernel_launch(void* const* d_in, const int* in_sizes, int n_in,
                              void* d_out, int out_size, void* d_ws, size_t ws_size,
                              hipStream_t stream) {
  const float* x    = (const float*)d_in[0];
  const float* Wih0 = (const float*)d_in[1];
  const float* Whh0 = (const float*)d_in[2];
  const float* bi0  = (const float*)d_in[3];
  const float* bh0  = (const float*)d_in[4];
  const float* Wih1 = (const float*)d_in[5];
  const float* Whh1 = (const float*)d_in[6];
  const float* bi1  = (const float*)d_in[7];
  const float* bh1  = (const float*)d_in[8];

  float* outy = (float*)d_out;
  float* outh = outy + (size_t)32 * 1024 * 1024;   // [2][32][1024] tail

  char* ws = (char*)d_ws;
  char* h0ring = ws;                        // RING x 131072 B (hi plane 64K + lo plane 64K)
  char* h1ring = ws + 1048576;              // 1 MB
  int*  flg    = (int*)(ws + 2097152);      // 64 flags x 16 B

  prep_kernel<<<128, 256, 0, stream>>>((unsigned int*)ws);
  rnn_fused<<<NWG, 256, 0, stream>>>(x, Wih0, Whh0, bi0, bh0,
                                     Wih1, Whh1, bi1, bh1,
                                     h0ring, h1ring, flg, outy, outh);
}

// Round 6
// 5832.542 us; speedup vs baseline: 1.8372x; 1.4401x over previous
//
#include <hip/hip_runtime.h>

#define T_LEN 1024
#define DIN   512
#define HID   1024
#define NWG   64
#define RING  8

typedef __attribute__((ext_vector_type(8))) short short8;  // 8 x bf16 bits
typedef __attribute__((ext_vector_type(4))) float f4;
typedef unsigned long long u64;
typedef unsigned short u16;

#define LD_AG(p)    __hip_atomic_load((p),  __ATOMIC_RELAXED, __HIP_MEMORY_SCOPE_AGENT)
#define ST_AG(p, v) __hip_atomic_store((p), (v), __ATOMIC_RELAXED, __HIP_MEMORY_SCOPE_AGENT)

// coherent 16B load/store (L1+L2 bypass -> L3 coherence point); plain 16B load
#define GLDC(dst, ptr) \
  asm volatile("global_load_dwordx4 %0, %1, off sc0 sc1" : "=v"(dst) : "v"(ptr))
#define GLDP(dst, ptr) \
  asm volatile("global_load_dwordx4 %0, %1, off" : "=v"(dst) : "v"(ptr))
#define GSTC(ptr, val) \
  asm volatile("global_store_dwordx4 %0, %1, off sc0 sc1" :: "v"(ptr), "v"(val) : "memory")

template<int N> __device__ __forceinline__ void waitv() {
  asm volatile("s_waitcnt vmcnt(%0)" :: "i"(N) : "memory");
  __builtin_amdgcn_sched_barrier(0);   // rule #18: pin MFMAs below the waitcnt
}

__device__ __forceinline__ u16 f2bf(float f) {
  union { float f; unsigned u; } v; v.f = f;
  return (u16)((v.u + 0x7FFFu + ((v.u >> 16) & 1u)) >> 16);  // RNE
}
__device__ __forceinline__ float bf2f(u16 b) {
  union { unsigned u; float f; } v; v.u = ((unsigned)b) << 16; return v.f;
}
__device__ __forceinline__ short8 cvt8(f4 a, f4 b) {
  short8 r;
  r[0]=(short)f2bf(a[0]); r[1]=(short)f2bf(a[1]); r[2]=(short)f2bf(a[2]); r[3]=(short)f2bf(a[3]);
  r[4]=(short)f2bf(b[0]); r[5]=(short)f2bf(b[1]); r[6]=(short)f2bf(b[2]); r[7]=(short)f2bf(b[3]);
  return r;
}
__device__ __forceinline__ void cvt8hl(f4 a, f4 b, short8& hi, short8& lo) {
  hi = cvt8(a, b);
  f4 ra, rb;
#pragma unroll
  for (int j = 0; j < 4; ++j) {
    ra[j] = a[j] - bf2f((u16)hi[j]);
    rb[j] = b[j] - bf2f((u16)hi[4 + j]);
  }
  lo = cvt8(ra, rb);
}
__device__ __forceinline__ float tanh_fast(float x) {
  float e = __expf(2.f * x);
  return 1.f - 2.f / (e + 1.f);
}
__device__ __forceinline__ f4 mfma16(short8 a, short8 b, f4 c) {
  return __builtin_amdgcn_mfma_f32_16x16x32_bf16(a, b, c, 0, 0, 0);
}
// 3-term compensated bf16 product
__device__ __forceinline__ f4 fma3(short8 ah, short8 al, short8 bh, short8 bl, f4 c) {
  c = mfma16(ah, bh, c);
  c = mfma16(al, bh, c);
  c = mfma16(ah, bl, c);
  return c;
}

// Zero parity-0 of both rings + flags.
__global__ void prep_kernel(unsigned int* __restrict__ z) {
  int i = blockIdx.x * 256 + threadIdx.x;          // 128 blocks -> 32768 threads
  z[i] = 0u;                                       // h0 parity 0 (128 KB)
  z[262144 + i] = 0u;                              // h1 parity 0
  if (i < 256) z[524288 + i] = 0u;                 // flags (1 KB)
}

// Per-layer persistent body. WG wg: output cols [(wg&31)*32,+32). 4 waves split K.
// Hi-weights in regs, lo-weights in LDS. Ring loads: asm sc0sc1 dwordx4, issued
// 3 groups ahead, counted-vmcnt consumption. Sync protocol identical to round 5.
template<int L>
__device__ __forceinline__ void rnn_body(
    const float* __restrict__ x,
    const float* __restrict__ Wih, const float* __restrict__ Whh,
    const float* __restrict__ bi,  const float* __restrict__ bh,
    char* __restrict__ h0ring, char* __restrict__ h1ring,
    int* __restrict__ flags,
    float* __restrict__ outy, float* __restrict__ outh,
    float* red, u16* trh, u16* trl, short8* wlo, int wg) {
  const int i_base = (wg & 31) * 32;
  const int tid  = threadIdx.x;
  const int wv   = tid >> 6;
  const int lane = tid & 63;
  const int l15  = lane & 15;
  const int kb   = lane >> 4;

  constexpr int K1   = L ? HID : DIN;
  constexpr int NPRE = L ? 8 : 4;
  char* ringW = L ? h1ring : h0ring;

  // ---- hoist weights: hi -> regs, lo -> LDS (slot: pre kk*2+nf, rec 16+kk*2+nf) ----
  short8 bpre[NPRE][2], brhi[8][2];
#pragma unroll
  for (int kk = 0; kk < NPRE; ++kk)
#pragma unroll
    for (int nf = 0; nf < 2; ++nf) {
      int k = wv * (K1 / 4) + kk * 32 + kb * 8;
      const float* sp = Wih + (size_t)(i_base + nf * 16 + l15) * K1 + k;
      short8 lo; cvt8hl(*(const f4*)sp, *(const f4*)(sp + 4), bpre[kk][nf], lo);
      wlo[(wv * 32 + kk * 2 + nf) * 64 + lane] = lo;
    }
#pragma unroll
  for (int kk = 0; kk < 8; ++kk)
#pragma unroll
    for (int nf = 0; nf < 2; ++nf) {
      int k = wv * 256 + kk * 32 + kb * 8;
      const float* sp = Whh + (size_t)(i_base + nf * 16 + l15) * HID + k;
      short8 lo; cvt8hl(*(const f4*)sp, *(const f4*)(sp + 4), brhi[kk][nf], lo);
      wlo[(wv * 32 + 16 + kk * 2 + nf) * 64 + lane] = lo;
    }
  __syncthreads();

  const int emh = wv & 1, enf = wv >> 1;
  const int e_i = i_base + enf * 16 + l15;
  const float biasv = bi[e_i] + bh[e_i];
  const int K32w = wg & 31;
  const int c_col = enf * 16 + l15;

  // split-layer wait mapping (round-5 proven)
  int fidx, foff;
  if (L == 0) { fidx = lane;                                foff = (lane < 32) ? 0 : -4; }
  else        { fidx = (lane < 32) ? (32 + lane) : (lane - 32); foff = (lane < 32) ? 0 : 1; }
  int* flagp = flags + fidx * 4;

#define ISS_REC(g) { \
    GLDC(gh0[(g)&3], rec + (g)*2048);         \
    GLDC(gl0[(g)&3], rec + (g)*2048 + 65536); \
    GLDC(gh1[(g)&3], rec + (g)*2048 + 1024);  \
    GLDC(gl1[(g)&3], rec + (g)*2048 + 66560); }
#define MF_REC(g, VC) { \
    short8 bl0 = wlo[(wv*32 + 16 + (g)*2 + 0)*64 + lane]; \
    short8 bl1 = wlo[(wv*32 + 16 + (g)*2 + 1)*64 + lane]; \
    waitv<VC>(); \
    acc0 = fma3(gh0[(g)&3], gl0[(g)&3], brhi[g][0], bl0, acc0); \
    acc1 = fma3(gh1[(g)&3], gl1[(g)&3], brhi[g][0], bl0, acc1); \
    acc2 = fma3(gh0[(g)&3], gl0[(g)&3], brhi[g][1], bl1, acc2); \
    acc3 = fma3(gh1[(g)&3], gl1[(g)&3], brhi[g][1], bl1, acc3); }
#define ISS_PRE(kk) { \
    GLDC(ph0[(kk)&3], pre + (kk)*2048);         \
    GLDC(ph1[(kk)&3], pre + (kk)*2048 + 1024); }
#define MF_PRE(kk, VC) { \
    short8 bl0 = wlo[(wv*32 + (kk)*2 + 0)*64 + lane]; \
    short8 bl1 = wlo[(wv*32 + (kk)*2 + 1)*64 + lane]; \
    waitv<VC>(); \
    acc0 = mfma16(ph0[(kk)&3], bpre[kk][0], acc0); \
    acc0 = mfma16(ph0[(kk)&3], bl0, acc0); \
    acc1 = mfma16(ph1[(kk)&3], bpre[kk][0], acc1); \
    acc1 = mfma16(ph1[(kk)&3], bl0, acc1); \
    acc2 = mfma16(ph0[(kk)&3], bpre[kk][1], acc2); \
    acc2 = mfma16(ph0[(kk)&3], bl1, acc2); \
    acc3 = mfma16(ph1[(kk)&3], bpre[kk][1], acc3); \
    acc3 = mfma16(ph1[(kk)&3], bl1, acc3); }

  for (int t = 0; t < T_LEN; ++t) {
    // ---- L0: issue x loads before the poll (latency hides under it) ----
    f4 xa[4][4];
    if constexpr (L == 0) {
      const float* xr0 = x + ((size_t)l15 * T_LEN + t) * DIN;
      const float* xr1 = x + ((size_t)(16 + l15) * T_LEN + t) * DIN;
#pragma unroll
      for (int kk = 0; kk < 4; ++kk) {
        int k = wv * 128 + kk * 32 + kb * 8;
        GLDP(xa[kk][0], (xr0 + k));
        GLDP(xa[kk][1], (xr0 + k + 4));
        GLDP(xa[kk][2], (xr1 + k));
        GLDP(xa[kk][3], (xr1 + k + 4));
      }
    }

    // ---- wave-lockstep flag poll (each lane one dep) ----
    {
      const int thr = t + foff;
      while (LD_AG(flagp) < thr) __builtin_amdgcn_s_sleep(1);
    }
    __builtin_amdgcn_sched_barrier(0);

    const char* rec = ringW + (size_t)(t & (RING - 1)) * 131072 + wv * 16384 + lane * 16;
    f4 acc0 = {0.f,0.f,0.f,0.f}, acc1 = acc0, acc2 = acc0, acc3 = acc0;
    short8 gh0[4], gl0[4], gh1[4], gl1[4];

    if constexpr (L == 0) {
      ISS_REC(0);
      waitv<4>();                         // x done (in-order retirement)
#pragma unroll
      for (int kk = 0; kk < 4; ++kk) {    // x-block overlaps rec0 latency
        short8 a0h, a0l, a1h, a1l;
        cvt8hl(xa[kk][0], xa[kk][1], a0h, a0l);
        cvt8hl(xa[kk][2], xa[kk][3], a1h, a1l);
        short8 bl0 = wlo[(wv*32 + kk*2 + 0)*64 + lane];
        short8 bl1 = wlo[(wv*32 + kk*2 + 1)*64 + lane];
        acc0 = fma3(a0h, a0l, bpre[kk][0], bl0, acc0);
        acc1 = fma3(a1h, a1l, bpre[kk][0], bl0, acc1);
        acc2 = fma3(a0h, a0l, bpre[kk][1], bl1, acc2);
        acc3 = fma3(a1h, a1l, bpre[kk][1], bl1, acc3);
      }
      ISS_REC(1); ISS_REC(2); ISS_REC(3);
      MF_REC(0, 12);
      ISS_REC(4); MF_REC(1, 12);
      ISS_REC(5); MF_REC(2, 12);
      ISS_REC(6); MF_REC(3, 12);
      ISS_REC(7); MF_REC(4, 12);
      MF_REC(5, 8); MF_REC(6, 4); MF_REC(7, 0);
    } else {
      const char* pre = h0ring + (size_t)((t + 1) & (RING - 1)) * 131072 + wv * 16384 + lane * 16;
      short8 ph0[4], ph1[4];
      ISS_REC(0); ISS_REC(1); ISS_REC(2);
      ISS_REC(3); MF_REC(0, 12);
      ISS_REC(4); MF_REC(1, 12);
      ISS_REC(5); MF_REC(2, 12);
      ISS_REC(6); MF_REC(3, 12);
      ISS_REC(7); MF_REC(4, 12);
      ISS_PRE(0); MF_REC(5, 10);
      ISS_PRE(1); MF_REC(6, 8);
      ISS_PRE(2); MF_REC(7, 6);
      ISS_PRE(3); MF_PRE(0, 6);
      ISS_PRE(4); MF_PRE(1, 6);
      ISS_PRE(5); MF_PRE(2, 6);
      ISS_PRE(6); MF_PRE(3, 6);
      ISS_PRE(7); MF_PRE(4, 6);
      MF_PRE(5, 4); MF_PRE(6, 2); MF_PRE(7, 0);
    }

    // ---- cross-wave K reduction via LDS ----
    *(f4*)&red[((wv * 4 + 0) * 64 + lane) * 4] = acc0;
    *(f4*)&red[((wv * 4 + 1) * 64 + lane) * 4] = acc1;
    *(f4*)&red[((wv * 4 + 2) * 64 + lane) * 4] = acc2;
    *(f4*)&red[((wv * 4 + 3) * 64 + lane) * 4] = acc3;
    __syncthreads();
    f4 tot = *(const f4*)&red[((0 * 4 + wv) * 64 + lane) * 4];
    tot += *(const f4*)&red[((1 * 4 + wv) * 64 + lane) * 4];
    tot += *(const f4*)&red[((2 * 4 + wv) * 64 + lane) * 4];
    tot += *(const f4*)&red[((3 * 4 + wv) * 64 + lane) * 4];

    // ---- bias + tanh; hi/lo split into LDS transpose tile ----
    float vkeep[4];
#pragma unroll
    for (int rr = 0; rr < 4; ++rr) {
      const int b = emh * 16 + kb * 4 + rr;
      float v = tanh_fast(tot[rr] + biasv);
      vkeep[rr] = v;
      u16 hi = f2bf(v);
      u16 lo = f2bf(v - bf2f(hi));
      trh[b * 36 + c_col] = hi;
      trl[b * 36 + c_col] = lo;
    }
    __syncthreads();

    // ---- coalesced coherent h-store (wave -> plane/half) ----
    {
      char* wr = ringW + (size_t)((t + 1) & (RING - 1)) * 131072 + (wv >> 1) * 65536;
      const int hf2 = wv & 1;
      const u16* srow = (wv >> 1) ? &trl[(hf2 * 16 + l15) * 36 + kb * 8]
                                  : &trh[(hf2 * 16 + l15) * 36 + kb * 8];
      union { u64 q[2]; short8 s; } uu;
      uu.q[0] = ((const u64*)srow)[0];
      uu.q[1] = ((const u64*)srow)[1];
      char* d = wr + (size_t)(((K32w * 2 + hf2) * 64 + lane) * 16);
      GSTC(d, uu.s);
    }

    // ---- outputs before the drain (share one vmcnt(0)) ----
    if constexpr (L == 0) {
      if (t == T_LEN - 1) {
#pragma unroll
        for (int rr = 0; rr < 4; ++rr)
          outh[(size_t)(emh * 16 + kb * 4 + rr) * HID + e_i] = vkeep[rr];
      }
    } else {
#pragma unroll
      for (int rr = 0; rr < 4; ++rr) {
        const int b = emh * 16 + kb * 4 + rr;
        float vo = __shfl_xor(vkeep[rr], 1, 64);
        if ((l15 & 1) == 0)
          *(float2*)&outy[((size_t)b * T_LEN + t) * HID + e_i] = make_float2(vkeep[rr], vo);
        if (t == T_LEN - 1) outh[32768 + (size_t)b * HID + e_i] = vkeep[rr];
      }
    }

    waitv<0>();          // drain h-stores (+outputs) before flag publish
    __syncthreads();
    if (tid == 0) ST_AG(flags + wg * 4, t + 1);
  }
#undef ISS_REC
#undef MF_REC
#undef ISS_PRE
#undef MF_PRE
}

__global__ __launch_bounds__(256, 1)
void rnn_fused(const float* __restrict__ x,
               const float* __restrict__ Wih0, const float* __restrict__ Whh0,
               const float* __restrict__ bi0,  const float* __restrict__ bh0,
               const float* __restrict__ Wih1, const float* __restrict__ Whh1,
               const float* __restrict__ bi1,  const float* __restrict__ bh1,
               char* __restrict__ h0ring, char* __restrict__ h1ring,
               int* __restrict__ flags,
               float* __restrict__ outy, float* __restrict__ outh) {
  __shared__ float  red[4 * 4 * 64 * 4];   // 16 KB
  __shared__ u16    trh[32 * 36];          // 2.25 KB
  __shared__ u16    trl[32 * 36];
  __shared__ short8 wlo[4 * 32 * 64];      // 128 KB lo-weights
  const int wg = blockIdx.x;
  if (wg < 32)
    rnn_body<0>(x, Wih0, Whh0, bi0, bh0, h0ring, h1ring, flags, outy, outh,
                red, trh, trl, wlo, wg);
  else
    rnn_body<1>(x, Wih1, Whh1, bi1, bh1, h0ring, h1ring, flags, outy, outh,
                red, trh, trl, wlo, wg);
}

extern "C" void kernel_launch(void* const* d_in, const int* in_sizes, int n_in,
                              void* d_out, int out_size, void* d_ws, size_t ws_size,
                              hipStream_t stream) {
  const float* x    = (const float*)d_in[0];
  const float* Wih0 = (const float*)d_in[1];
  const float* Whh0 = (const float*)d_in[2];
  const float* bi0  = (const float*)d_in[3];
  const float* bh0  = (const float*)d_in[4];
  const float* Wih1 = (const float*)d_in[5];
  const float* Whh1 = (const float*)d_in[6];
  const float* bi1  = (const float*)d_in[7];
  const float* bh1  = (const float*)d_in[8];

  float* outy = (float*)d_out;
  float* outh = outy + (size_t)32 * 1024 * 1024;   // [2][32][1024] tail

  char* ws = (char*)d_ws;
  char* h0ring = ws;                        // RING x 131072 B (hi plane 64K + lo plane 64K)
  char* h1ring = ws + 1048576;              // 1 MB
  int*  flg    = (int*)(ws + 2097152);      // 64 flags x 16 B

  prep_kernel<<<128, 256, 0, stream>>>((unsigned int*)ws);
  rnn_fused<<<NWG, 256, 0, stream>>>(x, Wih0, Whh0, bi0, bh0,
                                     Wih1, Whh1, bi1, bh1,
                                     h0ring, h1ring, flg, outy, outh);
}

// Round 10
// 3545.659 us; speedup vs baseline: 3.0222x; 1.6450x over previous
//
#include <hip/hip_runtime.h>

#define T_LEN 1024
#define DIN   512
#define HID   1024
#define GRID  128    // 64 WGs/layer: 32 col-slices x 2 batch-halves
#define RING  8
#define GUARD_CAP (1u << 18)   // poll watchdog: decay to fast wrong-answer, never hang

typedef __attribute__((ext_vector_type(8))) short short8;  // 8 x bf16 bits
typedef __attribute__((ext_vector_type(4))) float f4;
typedef unsigned long long u64;
typedef unsigned short u16;

#define LD_AG(p)    __hip_atomic_load((p),  __ATOMIC_RELAXED, __HIP_MEMORY_SCOPE_AGENT)
#define ST_AG(p, v) __hip_atomic_store((p), (v), __ATOMIC_RELAXED, __HIP_MEMORY_SCOPE_AGENT)

// L3-coherent 16B ops (proven round-6 path)
#define GLDC(dst, ptr) \
  asm volatile("global_load_dwordx4 %0, %1, off sc0 sc1" : "=v"(dst) : "v"(ptr))
#define GSTC(ptr, val) \
  asm volatile("global_store_dwordx4 %0, %1, off sc0 sc1" :: "v"(ptr), "v"(val) : "memory")
// plain cached 16B load (read-only x)
#define GLDP(dst, ptr) \
  asm volatile("global_load_dwordx4 %0, %1, off" : "=v"(dst) : "v"(ptr))

template<int N> __device__ __forceinline__ void waitv() {
  asm volatile("s_waitcnt vmcnt(%0)" :: "i"(N) : "memory");
  __builtin_amdgcn_sched_barrier(0);   // rule #18
}

__device__ __forceinline__ u16 f2bf(float f) {
  union { float f; unsigned u; } v; v.f = f;
  return (u16)((v.u + 0x7FFFu + ((v.u >> 16) & 1u)) >> 16);  // RNE
}
__device__ __forceinline__ float bf2f(u16 b) {
  union { unsigned u; float f; } v; v.u = ((unsigned)b) << 16; return v.f;
}
__device__ __forceinline__ short8 cvt8(f4 a, f4 b) {
  short8 r;
  r[0]=(short)f2bf(a[0]); r[1]=(short)f2bf(a[1]); r[2]=(short)f2bf(a[2]); r[3]=(short)f2bf(a[3]);
  r[4]=(short)f2bf(b[0]); r[5]=(short)f2bf(b[1]); r[6]=(short)f2bf(b[2]); r[7]=(short)f2bf(b[3]);
  return r;
}
__device__ __forceinline__ void cvt8hl(f4 a, f4 b, short8& hi, short8& lo) {
  hi = cvt8(a, b);
  f4 ra, rb;
#pragma unroll
  for (int j = 0; j < 4; ++j) {
    ra[j] = a[j] - bf2f((u16)hi[j]);
    rb[j] = b[j] - bf2f((u16)hi[4 + j]);
  }
  lo = cvt8(ra, rb);
}
__device__ __forceinline__ float tanh_fast(float x) {
  float e = __expf(2.f * x);
  return 1.f - 2.f / (e + 1.f);
}
__device__ __forceinline__ f4 mfma16(short8 a, short8 b, f4 c) {
  return __builtin_amdgcn_mfma_f32_16x16x32_bf16(a, b, c, 0, 0, 0);
}
__device__ __forceinline__ f4 fma3(short8 ah, short8 al, short8 bh, short8 bl, f4 c) {
  c = mfma16(ah, bh, c);
  c = mfma16(al, bh, c);
  c = mfma16(ah, bl, c);
  return c;
}

// zero parity-0 of both rings + flags (128 x 64B)
__global__ void prep_kernel(unsigned int* __restrict__ z) {
  int i = blockIdx.x * 256 + threadIdx.x;          // 128 blocks -> 32768 threads
  z[i] = 0u;                                       // h0 parity 0 (128 KB: hi+lo planes)
  z[262144 + i] = 0u;                              // h1 parity 0
  if (i < 2048) z[524288 + i] = 0u;                // flags (8 KB)
}

// Persistent fused 2-layer RNN, batch-split. Global WG id g (0..127):
//   layer = g>>6; within layer: wg = g&63, bh = (wg>>5)&1 (batch rows bh*16..+16),
//   cs = wg&31 (cols cs*32..+32). Flag slot = GLOBAL id g (fid) — round-9 bug was
//   L1 publishing into L0's slots (fid==wg); consumers poll L1 at 64+, never written.
// 4 waves split K. Hi-weights in regs, lo-weights in LDS. Full-step load prefetch:
// all rec(+pre) coherent loads issued up front, consumed under counted vmcnt.
// Sync protocol = round 6 (proven): single flag/WG, full drain before publish, all sc0 sc1.
template<int L>
__device__ __forceinline__ void rnn_body(
    const float* __restrict__ x,
    const float* __restrict__ Wih, const float* __restrict__ Whh,
    const float* __restrict__ bias_i, const float* __restrict__ bias_h,
    char* __restrict__ h0ring, char* __restrict__ h1ring,
    int* __restrict__ gfl,
    float* __restrict__ outy, float* __restrict__ outh,
    float* red, u16* trh, u16* trl, short8* wlo, int wg) {
  const int fid = L * 64 + wg;        // global flag slot (THE round-9 fix)
  const int cs = wg & 31;
  const int bh = (wg >> 5) & 1;
  const int i_base = cs * 32;
  const int tid  = threadIdx.x;
  const int wv   = tid >> 6;
  const int lane = tid & 63;
  const int l15  = lane & 15;
  const int kb   = lane >> 4;

  constexpr int K1   = L ? HID : DIN;
  constexpr int NPRE = L ? 8 : 4;
  char* ringW = L ? h1ring : h0ring;

  // ---- hoist weights: hi -> regs, lo -> LDS (slots: pre kk*2+nf, rec 16+kk*2+nf) ----
  short8 bpre[NPRE][2], brhi[8][2];
#pragma unroll
  for (int kk = 0; kk < NPRE; ++kk)
#pragma unroll
    for (int nf = 0; nf < 2; ++nf) {
      int k = wv * (K1 / 4) + kk * 32 + kb * 8;
      const float* sp = Wih + (size_t)(i_base + nf * 16 + l15) * K1 + k;
      short8 lo; cvt8hl(*(const f4*)sp, *(const f4*)(sp + 4), bpre[kk][nf], lo);
      wlo[(wv * 32 + kk * 2 + nf) * 64 + lane] = lo;
    }
#pragma unroll
  for (int kk = 0; kk < 8; ++kk)
#pragma unroll
    for (int nf = 0; nf < 2; ++nf) {
      int k = wv * 256 + kk * 32 + kb * 8;
      const float* sp = Whh + (size_t)(i_base + nf * 16 + l15) * HID + k;
      short8 lo; cvt8hl(*(const f4*)sp, *(const f4*)(sp + 4), brhi[kk][nf], lo);
      wlo[(wv * 32 + 16 + kk * 2 + nf) * 64 + lane] = lo;
    }
  __syncthreads();

  // epilogue constants (waves 0,1 finalize N-frag wv)
  const int e_i = i_base + (wv & 1) * 16 + l15;
  float biasv = 0.f;
  if (wv < 2) biasv = bias_i[e_i] + bias_h[e_i];
  const int c_col = (wv & 1) * 16 + l15;

  // ---- per-lane dependency mapping (round-6 thresholds, same-bh sets) ----
  // L0: lanes<32 -> L0 peers (bh) slots bh*32+ln  thr=t ; lanes>=32 -> L1 (bh) slots 64+bh*32+ln thr=t-4
  // L1: lanes<32 -> L1 peers (bh) slots 64+bh*32+ln thr=t ; lanes>=32 -> L0 (bh) slots bh*32+ln thr=t+1
  int fidx, foff;
  if (L == 0) {
    if (lane < 32) { fidx = bh * 32 + lane;             foff = 0;  }
    else           { fidx = 64 + bh * 32 + (lane - 32); foff = -4; }
  } else {
    if (lane < 32) { fidx = 64 + bh * 32 + lane;        foff = 0;  }
    else           { fidx = bh * 32 + (lane - 32);      foff = 1;  }
  }
  const int* flagp = gfl + fidx * 16;

#define ISSR(kk) { \
    GLDC(gh[kk], rec + (kk) * 2048); \
    GLDC(gl[kk], rec + (kk) * 2048 + 65536); }
#define ISSP(kk) { GLDC(ph[kk], pre + (kk) * 2048); }
#define MFR(kk, VC) { \
    short8 bl0 = wlo[(wv * 32 + 16 + (kk) * 2 + 0) * 64 + lane]; \
    short8 bl1 = wlo[(wv * 32 + 16 + (kk) * 2 + 1) * 64 + lane]; \
    waitv<VC>(); \
    acc0 = fma3(gh[kk], gl[kk], brhi[kk][0], bl0, acc0); \
    acc1 = fma3(gh[kk], gl[kk], brhi[kk][1], bl1, acc1); }
#define MFP(kk, VC) { \
    short8 bl0 = wlo[(wv * 32 + (kk) * 2 + 0) * 64 + lane]; \
    short8 bl1 = wlo[(wv * 32 + (kk) * 2 + 1) * 64 + lane]; \
    waitv<VC>(); \
    acc0 = mfma16(ph[kk], bpre[kk][0], acc0); \
    acc0 = mfma16(ph[kk], bl0, acc0); \
    acc1 = mfma16(ph[kk], bpre[kk][1], acc1); \
    acc1 = mfma16(ph[kk], bl1, acc1); }

  for (int t = 0; t < T_LEN; ++t) {
    // ---- L0: issue x loads before the poll (poll's flag-load wait drains them) ----
    f4 xa[8];
    if constexpr (L == 0) {
      const float* xr = x + ((size_t)(bh * 16 + l15) * T_LEN + t) * DIN;
#pragma unroll
      for (int kk = 0; kk < 4; ++kk) {
        int k = wv * 128 + kk * 32 + kb * 8;
        GLDP(xa[kk * 2],     (xr + k));
        GLDP(xa[kk * 2 + 1], (xr + k + 4));
      }
    }

    // ---- wave-lockstep guarded poll (each lane one dep) ----
    {
      const int thr = t + foff;
      unsigned gd = 0;
      while (LD_AG(flagp) < thr) {
        if (++gd > GUARD_CAP) break;
        __builtin_amdgcn_s_sleep(1);
      }
    }
    __builtin_amdgcn_sched_barrier(0);

    const char* rec = ringW + (size_t)(t & (RING - 1)) * 131072
                      + wv * 16384 + bh * 1024 + lane * 16;
    f4 acc0 = {0.f,0.f,0.f,0.f}, acc1 = acc0;
    short8 gh[8], gl[8];

    if constexpr (L == 0) {
      // issue the WHOLE step's rec loads up front (16 in flight)
      ISSR(0); ISSR(1); ISSR(2); ISSR(3); ISSR(4); ISSR(5); ISSR(6); ISSR(7);
      // x-block (data already drained by the poll) overlaps the rec flight
#pragma unroll
      for (int kk = 0; kk < 4; ++kk) {
        short8 a0h, a0l;
        cvt8hl(xa[kk * 2], xa[kk * 2 + 1], a0h, a0l);
        short8 bl0 = wlo[(wv * 32 + kk * 2 + 0) * 64 + lane];
        short8 bl1 = wlo[(wv * 32 + kk * 2 + 1) * 64 + lane];
        acc0 = fma3(a0h, a0l, bpre[kk][0], bl0, acc0);
        acc1 = fma3(a0h, a0l, bpre[kk][1], bl1, acc1);
      }
      MFR(0, 14); MFR(1, 12); MFR(2, 10); MFR(3, 8);
      MFR(4, 6);  MFR(5, 4);  MFR(6, 2);  MFR(7, 0);
    } else {
      const char* pre = h0ring + (size_t)((t + 1) & (RING - 1)) * 131072
                        + wv * 16384 + bh * 1024 + lane * 16;
      short8 ph[8];
      // 24 loads in flight: 16 rec + 8 pre (hi-only y0)
      ISSR(0); ISSR(1); ISSR(2); ISSR(3); ISSR(4); ISSR(5); ISSR(6); ISSR(7);
      ISSP(0); ISSP(1); ISSP(2); ISSP(3); ISSP(4); ISSP(5); ISSP(6); ISSP(7);
      MFR(0, 22); MFR(1, 20); MFR(2, 18); MFR(3, 16);
      MFR(4, 14); MFR(5, 12); MFR(6, 10); MFR(7, 8);
      MFP(0, 7); MFP(1, 6); MFP(2, 5); MFP(3, 4);
      MFP(4, 3); MFP(5, 2); MFP(6, 1); MFP(7, 0);
    }

    // ---- cross-wave K reduction via LDS (8 KB) ----
    *(f4*)&red[((wv * 2 + 0) * 64 + lane) * 4] = acc0;
    *(f4*)&red[((wv * 2 + 1) * 64 + lane) * 4] = acc1;
    __syncthreads();

    float vkeep[4];
    if (wv < 2) {
      f4 tot = *(const f4*)&red[((0 * 2 + wv) * 64 + lane) * 4];
      tot += *(const f4*)&red[((1 * 2 + wv) * 64 + lane) * 4];
      tot += *(const f4*)&red[((2 * 2 + wv) * 64 + lane) * 4];
      tot += *(const f4*)&red[((3 * 2 + wv) * 64 + lane) * 4];
      // C/D layout: col = lane&15, row = (lane>>4)*4 + reg  [m89]
#pragma unroll
      for (int rr = 0; rr < 4; ++rr) {
        const int bl = kb * 4 + rr;               // row 0..15 of this batch-half
        float v = tanh_fast(tot[rr] + biasv);
        vkeep[rr] = v;
        u16 hi = f2bf(v);
        u16 lo = f2bf(v - bf2f(hi));
        trh[bl * 36 + c_col] = hi;
        trl[bl * 36 + c_col] = lo;
      }
    }
    __syncthreads();   // tile ready

    // ---- stores: waves 2,3 do the coalesced ring stores; waves 0,1 do outputs ----
    if (wv >= 2) {
      const u16* srow = (wv == 2) ? &trh[(lane & 15) * 36 + (lane >> 4) * 8]
                                  : &trl[(lane & 15) * 36 + (lane >> 4) * 8];
      union { u64 q[2]; short8 s; } uu;
      uu.q[0] = ((const u64*)srow)[0];
      uu.q[1] = ((const u64*)srow)[1];
      char* d = ringW + (size_t)((t + 1) & (RING - 1)) * 131072
                + (wv == 3 ? 65536 : 0)
                + (size_t)(((cs * 2 + bh) * 64 + lane) * 16);
      GSTC(d, uu.s);
    } else {
      if constexpr (L == 1) {
#pragma unroll
        for (int rr = 0; rr < 4; ++rr) {
          const int brow = bh * 16 + kb * 4 + rr;
          float vo = __shfl_xor(vkeep[rr], 1, 64);
          if ((l15 & 1) == 0)
            *(float2*)&outy[((size_t)brow * T_LEN + t) * HID + e_i] = make_float2(vkeep[rr], vo);
        }
      }
      if (t == T_LEN - 1) {
#pragma unroll
        for (int rr = 0; rr < 4; ++rr) {
          const int brow = bh * 16 + kb * 4 + rr;
          outh[(size_t)L * 32768 + (size_t)brow * HID + e_i] = vkeep[rr];
        }
      }
    }

    waitv<0>();        // drain ALL stores (h-ring + outputs) before publish
    __syncthreads();
    if (tid == 0) ST_AG(gfl + fid * 16, t + 1);
  }
#undef ISSR
#undef ISSP
#undef MFR
#undef MFP
}

__global__ __launch_bounds__(256, 1)
void rnn_fused(const float* __restrict__ x,
               const float* __restrict__ Wih0, const float* __restrict__ Whh0,
               const float* __restrict__ bi0,  const float* __restrict__ bh0,
               const float* __restrict__ Wih1, const float* __restrict__ Whh1,
               const float* __restrict__ bi1,  const float* __restrict__ bh1,
               char* __restrict__ h0ring, char* __restrict__ h1ring,
               int* __restrict__ gfl,
               float* __restrict__ outy, float* __restrict__ outh) {
  __shared__ float  red[8 * 64 * 4];       // 8 KB
  __shared__ u16    trh[16 * 36];          // 1.125 KB
  __shared__ u16    trl[16 * 36];
  __shared__ short8 wlo[4 * 32 * 64];      // 128 KB lo-weights
  const int wg = blockIdx.x;
  if (wg < 64)
    rnn_body<0>(x, Wih0, Whh0, bi0, bh0, h0ring, h1ring, gfl, outy, outh,
                red, trh, trl, wlo, wg);
  else
    rnn_body<1>(x, Wih1, Whh1, bi1, bh1, h0ring, h1ring, gfl, outy, outh,
                red, trh, trl, wlo, wg - 64);
}

extern "C" void kernel_launch(void* const* d_in, const int* in_sizes, int n_in,
                              void* d_out, int out_size, void* d_ws, size_t ws_size,
                              hipStream_t stream) {
  const float* x    = (const float*)d_in[0];
  const float* Wih0 = (const float*)d_in[1];
  const float* Whh0 = (const float*)d_in[2];
  const float* bi0  = (const float*)d_in[3];
  const float* bh0  = (const float*)d_in[4];
  const float* Wih1 = (const float*)d_in[5];
  const float* Whh1 = (const float*)d_in[6];
  const float* bi1  = (const float*)d_in[7];
  const float* bh1  = (const float*)d_in[8];

  float* outy = (float*)d_out;
  float* outh = outy + (size_t)32 * 1024 * 1024;   // [2][32][1024] tail

  char* ws = (char*)d_ws;
  char* h0ring = ws;                        // RING x 131072 B (hi plane 64K + lo plane 64K)
  char* h1ring = ws + 1048576;              // 1 MB
  int*  gfl    = (int*)(ws + 2097152);      // 128 flags x 64 B

  prep_kernel<<<128, 256, 0, stream>>>((unsigned int*)ws);
  rnn_fused<<<GRID, 256, 0, stream>>>(x, Wih0, Whh0, bi0, bh0,
                                      Wih1, Whh1, bi1, bh1,
                                      h0ring, h1ring, gfl, outy, outh);
}